// Round 3
// baseline (221.620 us; speedup 1.0000x reference)
//
#include <hip/hip_runtime.h>

// EdgeEncoding, two kernels:
//   1) ee_bounds: per-source entry ranges offs[0..N] from the pid/N transitions
//      (entries are grouped by source s = pid/N, groups in increasing s, every
//      group non-empty because s always reaches itself).
//   2) ee_fused: one block per source. edge_attr staged in LDS, segment-sum in
//      stride-5 LDS (banks fully covered: 5 coprime 32), fused W/b epilogue.
//
// R1 post-mortem: traffic was ideal (64MB write + 23MB read) but latency-bound
// (occ 25%, VALUBusy 3%): small grid, serial gather chains, per-block binary
// search, 8-way LDS-atomic bank aliasing. This round attacks all four.
//
// Inputs (setup_inputs order):
//   0: x[N*64] f32 (UNUSED)  1: edge_attr[N*4] f32  2: W[16*4] f32  3: b[16] f32
//   4: pair_id[P] i32  5: node_id[P] i32  6: path_len[N*N] i32
// Output: [16, N, N] f32.

#define BS 1024
#define LSTRIDE 5

__global__ __launch_bounds__(256) void ee_bounds(
    const int* __restrict__ pair_id, int* __restrict__ offs, int P, int N)
{
    int p = blockIdx.x * 256 + threadIdx.x;
    if (p >= P) return;
    unsigned sa = (unsigned)pair_id[p] / (unsigned)N;
    if (p == 0) { offs[0] = 0; offs[N] = P; }
    if (p + 1 < P) {
        unsigned sb = (unsigned)pair_id[p + 1] / (unsigned)N;
        if (sb != sa) offs[sb] = p + 1;   // groups non-empty => sb == sa+1
    }
}

__global__ __launch_bounds__(BS) void ee_fused(
    const float* __restrict__ edge_attr,
    const float* __restrict__ W,
    const float* __restrict__ b,
    const int*   __restrict__ pair_id,
    const int*   __restrict__ node_id,
    const int*   __restrict__ path_len,
    const int*   __restrict__ offs,
    float*       __restrict__ out,
    int N, int NN)
{
    __shared__ float lsum[LSTRIDE * 1024 + 4];      // stride-5: banks 5q+c cover all 32
    __shared__ __align__(16) float sea[4 * 1024];   // edge_attr staged (16 KB)
    __shared__ float sW[64];
    __shared__ float sbv[16];

    const int tid   = threadIdx.x;
    const int s     = blockIdx.x;
    const int sbase = s * N;

    for (int i = tid; i < LSTRIDE * 1024 + 4; i += BS) lsum[i] = 0.0f;
    for (int i = tid; i < N; i += BS)
        reinterpret_cast<float4*>(sea)[i] = reinterpret_cast<const float4*>(edge_attr)[i];
    if (tid < 64) sW[tid] = W[tid];
    if (tid < 16) sbv[tid] = b[tid];

    const int lo = offs[s];
    const int hi = offs[s + 1];
    __syncthreads();

    // Scatter: 4 independent entries per thread-iteration for ILP.
    for (int p = lo + tid; p < hi; p += 4 * BS) {
        const int pB = p + BS, pC = p + 2 * BS, pD = p + 3 * BS;
        const bool vB = pB < hi, vC = pC < hi, vD = pD < hi;

        int pidA = pair_id[p];
        int nidA = node_id[p];
        int pidB = vB ? pair_id[pB] : 0;
        int nidB = vB ? node_id[pB] : 0;
        int pidC = vC ? pair_id[pC] : 0;
        int nidC = vC ? node_id[pC] : 0;
        int pidD = vD ? pair_id[pD] : 0;
        int nidD = vD ? node_id[pD] : 0;

        float4 eA = reinterpret_cast<const float4*>(sea)[nidA];
        float* dA = lsum + (pidA - sbase) * LSTRIDE;
        atomicAdd(dA + 0, eA.x); atomicAdd(dA + 1, eA.y);
        atomicAdd(dA + 2, eA.z); atomicAdd(dA + 3, eA.w);

        if (vB) {
            float4 e = reinterpret_cast<const float4*>(sea)[nidB];
            float* d = lsum + (pidB - sbase) * LSTRIDE;
            atomicAdd(d + 0, e.x); atomicAdd(d + 1, e.y);
            atomicAdd(d + 2, e.z); atomicAdd(d + 3, e.w);
        }
        if (vC) {
            float4 e = reinterpret_cast<const float4*>(sea)[nidC];
            float* d = lsum + (pidC - sbase) * LSTRIDE;
            atomicAdd(d + 0, e.x); atomicAdd(d + 1, e.y);
            atomicAdd(d + 2, e.z); atomicAdd(d + 3, e.w);
        }
        if (vD) {
            float4 e = reinterpret_cast<const float4*>(sea)[nidD];
            float* d = lsum + (pidD - sbase) * LSTRIDE;
            atomicAdd(d + 0, e.x); atomicAdd(d + 1, e.y);
            atomicAdd(d + 2, e.z); atomicAdd(d + 3, e.w);
        }
    }
    __syncthreads();

    // Epilogue: one pair per thread, 16 coalesced dword stores (one per h-plane).
    for (int q = tid; q < N; q += BS) {
        int L = path_len[sbase + q];
        float f = (L > 0) ? 1.0f / (float)L : 0.0f;
        float g = (L > 0) ? 1.0f : 0.0f;
        float v0 = lsum[q * LSTRIDE + 0];
        float v1 = lsum[q * LSTRIDE + 1];
        float v2 = lsum[q * LSTRIDE + 2];
        float v3 = lsum[q * LSTRIDE + 3];
#pragma unroll
        for (int h = 0; h < 16; ++h) {
            out[(size_t)h * NN + sbase + q] =
                (v0 * sW[4 * h + 0] + v1 * sW[4 * h + 1] +
                 v2 * sW[4 * h + 2] + v3 * sW[4 * h + 3]) * f + sbv[h] * g;
        }
    }
}

extern "C" void kernel_launch(void* const* d_in, const int* in_sizes, int n_in,
                              void* d_out, int out_size, void* d_ws, size_t ws_size,
                              hipStream_t stream) {
    const float* edge_attr = (const float*)d_in[1];
    const float* W         = (const float*)d_in[2];
    const float* b         = (const float*)d_in[3];
    const int*   pair_id   = (const int*)d_in[4];
    const int*   node_id   = (const int*)d_in[5];
    const int*   path_len  = (const int*)d_in[6];
    const int P  = in_sizes[4];
    const int NN = in_sizes[6];
    const int N  = in_sizes[0] / 64;       // x is [N, 64]

    int*   offs = (int*)d_ws;              // [N+1]
    float* out  = (float*)d_out;           // [16, NN]

    ee_bounds<<<(P + 255) / 256, 256, 0, stream>>>(pair_id, offs, P, N);
    ee_fused<<<N, BS, 0, stream>>>(edge_attr, W, b, pair_id, node_id, path_len,
                                   offs, out, N, NN);
}

// Round 4
// 123.481 us; speedup vs baseline: 1.7948x; 1.7948x over previous
//
#include <hip/hip_runtime.h>

// EdgeEncoding, two kernels:
//   1) ee_bounds: per-source entry ranges offs[0..N] from pid/N transitions.
//   2) ee_fused: one block per source s. ATOMIC-FREE segment sum:
//      entries for s are stored BFS-level by BFS-level ("chunks"), and within
//      a chunk all pids are distinct -> plain float4 RMW into LDS is race-free;
//      __syncthreads() between chunks. Chunk sizes cnt[c] = #{j: path_len>c}
//      are recomputed per block from the path_len row via wave ballots.
//
// R2 post-mortem: 17M ds_add_f32 lane-atomics serialize (~1/cy/CU); occupancy/
// ILP/bank changes were all neutral. This round removes LDS atomics entirely.
//
// Inputs (setup_inputs order):
//   0: x[N*64] f32 (UNUSED)  1: edge_attr[N*4] f32  2: W[16*4] f32  3: b[16] f32
//   4: pair_id[P] i32  5: node_id[P] i32  6: path_len[N*N] i32
// Output: [16, N, N] f32.

#define BS 512
#define NMAX 1024

__global__ __launch_bounds__(256) void ee_bounds(
    const int* __restrict__ pair_id, int* __restrict__ offs, int P, int N)
{
    int p = blockIdx.x * 256 + threadIdx.x;
    if (p >= P) return;
    unsigned sa = (unsigned)pair_id[p] / (unsigned)N;
    if (p == 0) { offs[0] = 0; offs[N] = P; }
    if (p + 1 < P) {
        unsigned sb = (unsigned)pair_id[p + 1] / (unsigned)N;
        if (sb != sa) offs[sb] = p + 1;   // groups non-empty => sb == sa+1
    }
}

__global__ __launch_bounds__(BS) void ee_fused(
    const float* __restrict__ edge_attr,
    const float* __restrict__ W,
    const float* __restrict__ b,
    const int*   __restrict__ pair_id,
    const int*   __restrict__ node_id,
    const int*   __restrict__ path_len,
    const int*   __restrict__ offs,
    float*       __restrict__ out,
    int N, int NN)
{
    __shared__ __align__(16) float4 sea[NMAX];    // edge_attr staged, 16 KB
    __shared__ __align__(16) float4 lsum[NMAX];   // per-pair sums, 16 KB
    __shared__ int   sstart[NMAX + 2];            // chunk starts (excl scan), 4.1 KB
    __shared__ float sW[64];
    __shared__ float sbv[16];
    __shared__ int   smaxd;

    const int tid   = threadIdx.x;
    const int s     = blockIdx.x;
    const int sbase = s * N;

    // ---- phase A: zero + stage + load path_len row ----
    if (tid == 0) smaxd = 0;
    for (int i = tid; i < N; i += BS) {
        lsum[i] = make_float4(0.f, 0.f, 0.f, 0.f);
        sea[i]  = reinterpret_cast<const float4*>(edge_attr)[i];
    }
    for (int i = tid; i < NMAX + 2; i += BS) sstart[i] = 0;
    if (tid < 64) sW[tid]  = W[tid];
    if (tid < 16) sbv[tid] = b[tid];

    const int j0 = tid, j1 = tid + BS;
    const int L0 = (j0 < N) ? path_len[sbase + j0] : 0;
    const int L1 = (j1 < N) ? path_len[sbase + j1] : 0;
    const int lo = offs[s];
    __syncthreads();

    // ---- phase B: maxd = max path_len over the row ----
    int m = max(L0, L1);
    for (int o = 32; o > 0; o >>= 1) m = max(m, __shfl_down(m, o));
    if ((tid & 63) == 0) atomicMax(&smaxd, m);
    __syncthreads();
    const int maxd = smaxd;

    // ---- phase C: chunk sizes via ballots; cnt[c] accumulated into sstart[c+1]
    for (int c = 0; c < maxd; ++c) {
        unsigned long long b0 = __ballot(L0 > c);
        unsigned long long b1 = __ballot(L1 > c);
        if ((tid & 63) == 0)
            atomicAdd(&sstart[c + 1], __popcll(b0) + __popcll(b1));
    }
    __syncthreads();
    if (tid == 0)  // exclusive scan (maxd is small; serial)
        for (int c = 1; c <= maxd; ++c) sstart[c] += sstart[c - 1];
    __syncthreads();

    // ---- phase D: chunk-synchronous atomic-free scatter ----
    // Thread owns positions p === tid (mod BS) within each chunk window;
    // chunk <= N = 2*BS so at most 2 entries per thread per chunk.
    int cp0, cp1; bool cv0, cv1;
    {
        int a0 = sstart[0], a1 = sstart[1];
        cp0 = a0 + ((tid - a0) & (BS - 1));
        cp1 = cp0 + BS;
        cv0 = cp0 < a1; cv1 = cp1 < a1;
    }
    int pidA = 0, nidA = 0, pidB = 0, nidB = 0;
    if (cv0) { pidA = pair_id[lo + cp0]; nidA = node_id[lo + cp0]; }
    if (cv1) { pidB = pair_id[lo + cp1]; nidB = node_id[lo + cp1]; }

    for (int c = 0; c < maxd; ++c) {
        // prefetch next chunk's index loads (global; no LDS hazard)
        bool nv0 = false, nv1 = false;
        int npA = 0, nnA = 0, npB = 0, nnB = 0;
        if (c + 1 < maxd) {
            int a0 = sstart[c + 1], a1 = sstart[c + 2];
            int q0 = a0 + ((tid - a0) & (BS - 1));
            int q1 = q0 + BS;
            nv0 = q0 < a1; nv1 = q1 < a1;
            if (nv0) { npA = pair_id[lo + q0]; nnA = node_id[lo + q0]; }
            if (nv1) { npB = pair_id[lo + q1]; nnB = node_id[lo + q1]; }
        }
        // process current chunk: plain RMW, pids distinct within a chunk
        if (cv0) {
            float4 e = sea[nidA];
            int q = pidA - sbase;
            float4 a = lsum[q];
            a.x += e.x; a.y += e.y; a.z += e.z; a.w += e.w;
            lsum[q] = a;
        }
        if (cv1) {
            float4 e = sea[nidB];
            int q = pidB - sbase;
            float4 a = lsum[q];
            a.x += e.x; a.y += e.y; a.z += e.z; a.w += e.w;
            lsum[q] = a;
        }
        __syncthreads();
        cv0 = nv0; cv1 = nv1;
        pidA = npA; nidA = nnA; pidB = npB; nidB = nnB;
    }

    // ---- phase E: fused W/b epilogue, 16 coalesced stores per pair ----
#pragma unroll
    for (int rep = 0; rep < 2; ++rep) {
        int q = tid + rep * BS;
        int L = rep ? L1 : L0;
        if (q < N) {
            float f = (L > 0) ? 1.0f / (float)L : 0.0f;
            float g = (L > 0) ? 1.0f : 0.0f;
            float4 v = lsum[q];
#pragma unroll
            for (int h = 0; h < 16; ++h) {
                out[(size_t)h * NN + sbase + q] =
                    (v.x * sW[4 * h + 0] + v.y * sW[4 * h + 1] +
                     v.z * sW[4 * h + 2] + v.w * sW[4 * h + 3]) * f + sbv[h] * g;
            }
        }
    }
}

extern "C" void kernel_launch(void* const* d_in, const int* in_sizes, int n_in,
                              void* d_out, int out_size, void* d_ws, size_t ws_size,
                              hipStream_t stream) {
    const float* edge_attr = (const float*)d_in[1];
    const float* W         = (const float*)d_in[2];
    const float* b         = (const float*)d_in[3];
    const int*   pair_id   = (const int*)d_in[4];
    const int*   node_id   = (const int*)d_in[5];
    const int*   path_len  = (const int*)d_in[6];
    const int P  = in_sizes[4];
    const int NN = in_sizes[6];
    const int N  = in_sizes[0] / 64;       // x is [N, 64]

    int*   offs = (int*)d_ws;              // [N+1]
    float* out  = (float*)d_out;           // [16, NN]

    ee_bounds<<<(P + 255) / 256, 256, 0, stream>>>(pair_id, offs, P, N);
    ee_fused<<<N, BS, 0, stream>>>(edge_attr, W, b, pair_id, node_id, path_len,
                                   offs, out, N, NN);
}